// Round 1
// baseline (179.728 us; speedup 1.0000x reference)
//
#include <hip/hip_runtime.h>

#define N_ 2
#define C_ 256
#define SP 512
#define H1 128
#define H2 64
#define H3 32

// A[n*SP+i][k] = sum_c points[n][c][i] * W0[c][k] + 0.5*b0[k]
// (half of b0 baked into each row so A_i + A_j = X@W0 + b0)
__global__ __launch_bounds__(128) void k_precompA(
    const float* __restrict__ points, const float* __restrict__ W0,
    const float* __restrict__ b0, float* __restrict__ A)
{
    int ni = blockIdx.x;               // n*512 + i
    int n = ni >> 9, i = ni & (SP - 1);
    int k = threadIdx.x;               // 0..127
    const float* pb = points + (size_t)n * C_ * SP + i;
    float acc = 0.5f * b0[k];
#pragma unroll 8
    for (int c = 0; c < C_; ++c)
        acc = fmaf(pb[(size_t)c * SP], W0[c * H1 + k], acc);   // pb[] wave-uniform -> s_load
    A[(size_t)ni * H1 + k] = acc;
}

__global__ __launch_bounds__(256) void k_main(
    const float* __restrict__ A,
    const float* __restrict__ W1, const float* __restrict__ b1,
    const float* __restrict__ W2, const float* __restrict__ b2,
    const float* __restrict__ W3, const float* __restrict__ b3,
    const float* __restrict__ heat, const float* __restrict__ mask,
    const float* __restrict__ pos,
    float* __restrict__ pred, float* __restrict__ accum)
{
    int n = blockIdx.z;
    int i = (blockIdx.y << 4) + (threadIdx.x >> 4);
    int j = (blockIdx.x << 4) + (threadIdx.x & 15);
    const float* Ai = A + (size_t)(n * SP + i) * H1;
    const float* Aj = A + (size_t)(n * SP + j) * H1;

    // layer 2: a2 = relu(Ai+Aj) @ W1 + b1   (x1 computed on the fly, never stored)
    float a2[H2];
#pragma unroll
    for (int o = 0; o < H2; ++o) a2[o] = b1[o];          // uniform -> s_load
#pragma unroll 4
    for (int k = 0; k < H1; ++k) {
        float x1 = fmaxf(Ai[k] + Aj[k], 0.0f);
#pragma unroll
        for (int o = 0; o < H2; ++o)
            a2[o] = fmaf(x1, W1[k * H2 + o], a2[o]);     // W1 uniform -> s_load
    }

    // layer 3: a3 = relu(a2) @ W2 + b2
    float a3[H3];
#pragma unroll
    for (int o = 0; o < H3; ++o) a3[o] = b2[o];
#pragma unroll 2
    for (int k = 0; k < H2; ++k) {
        float x2 = fmaxf(a2[k], 0.0f);
#pragma unroll
        for (int o = 0; o < H3; ++o)
            a3[o] = fmaf(x2, W2[k * H3 + o], a3[o]);
    }

    // layer 4: z = relu(a3) @ W3 + b3   (4 partial chains to break latency)
    float zp[4] = {0.f, 0.f, 0.f, 0.f};
#pragma unroll
    for (int k = 0; k < H3; ++k)
        zp[k & 3] = fmaf(fmaxf(a3[k], 0.0f), W3[k], zp[k & 3]);
    float z = b3[0] + ((zp[0] + zp[1]) + (zp[2] + zp[3]));

    size_t idx = ((size_t)n * SP + i) * SP + j;
    pred[idx] = z;

    // stable BCE-with-logits * mask * positiveMask
    float tg = heat[idx], mk = mask[idx], pm = pos[idx];
    float l = fmaxf(z, 0.0f) - z * tg + log1pf(expf(-fabsf(z)));
    float num = l * mk * pm;
    float den = pm;

    // wave(64)-level reduce, then cross-wave via LDS, one atomic pair per block
#pragma unroll
    for (int off = 32; off > 0; off >>= 1) {
        num += __shfl_down(num, off, 64);
        den += __shfl_down(den, off, 64);
    }
    __shared__ float rb[8];
    int lane = threadIdx.x & 63, wid = threadIdx.x >> 6;
    if (lane == 0) { rb[wid] = num; rb[4 + wid] = den; }
    __syncthreads();
    if (threadIdx.x == 0) {
        atomicAdd(&accum[0], (rb[0] + rb[1]) + (rb[2] + rb[3]));
        atomicAdd(&accum[1], (rb[4] + rb[5]) + (rb[6] + rb[7]));
    }
}

__global__ void k_final(const float* __restrict__ accum, float* __restrict__ out)
{
    out[0] = accum[0] / accum[1];
}

extern "C" void kernel_launch(void* const* d_in, const int* in_sizes, int n_in,
                              void* d_out, int out_size, void* d_ws, size_t ws_size,
                              hipStream_t stream)
{
    const float* points = (const float*)d_in[0];
    const float* heat   = (const float*)d_in[1];
    const float* mask   = (const float*)d_in[2];
    const float* pos    = (const float*)d_in[3];
    const float* W0     = (const float*)d_in[4];
    const float* b0     = (const float*)d_in[5];
    const float* W1     = (const float*)d_in[6];
    const float* b1     = (const float*)d_in[7];
    const float* W2     = (const float*)d_in[8];
    const float* b2     = (const float*)d_in[9];
    const float* W3     = (const float*)d_in[10];
    const float* b3     = (const float*)d_in[11];

    float* pred  = (float*)d_out;                       // (2,512,512)
    float* loss  = pred + (size_t)N_ * SP * SP;         // scalar
    float* accum = (float*)d_ws;                        // [0]=num, [1]=den
    float* A     = (float*)((char*)d_ws + 256);         // 2*512*128 f32 = 512 KiB

    hipMemsetAsync(d_ws, 0, 256, stream);
    k_precompA<<<N_ * SP, H1, 0, stream>>>(points, W0, b0, A);
    k_main<<<dim3(SP / 16, SP / 16, N_), 256, 0, stream>>>(
        A, W1, b1, W2, b2, W3, b3, heat, mask, pos, pred, accum);
    k_final<<<1, 1, 0, stream>>>(accum, loss);
}

// Round 2
// 169.735 us; speedup vs baseline: 1.0589x; 1.0589x over previous
//
#include <hip/hip_runtime.h>

#define N_ 2
#define C_ 256
#define SP 512
#define H1 128
#define H2 64
#define H3 32

// A[n*SP+i][k] = sum_c points[n][c][i] * W0[c][k] + 0.5*b0[k]
// (half of b0 baked into each row so A_i + A_j = X@W0 + b0)
__global__ __launch_bounds__(128) void k_precompA(
    const float* __restrict__ points, const float* __restrict__ W0,
    const float* __restrict__ b0, float* __restrict__ A)
{
    int ni = blockIdx.x;               // n*512 + i
    int n = ni >> 9, i = ni & (SP - 1);
    int k = threadIdx.x;               // 0..127
    const float* pb = points + (size_t)n * C_ * SP + i;
    float acc = 0.5f * b0[k];
#pragma unroll 8
    for (int c = 0; c < C_; ++c)
        acc = fmaf(pb[(size_t)c * SP], W0[c * H1 + k], acc);   // pb[] wave-uniform -> s_load
    A[(size_t)ni * H1 + k] = acc;
}

__global__ __launch_bounds__(256) void k_main(
    const float* __restrict__ A,
    const float* __restrict__ W1, const float* __restrict__ b1,
    const float* __restrict__ W2, const float* __restrict__ b2,
    const float* __restrict__ W3, const float* __restrict__ b3,
    const float* __restrict__ heat, const float* __restrict__ mask,
    const float* __restrict__ pos,
    float* __restrict__ pred, float* __restrict__ accum)
{
    int n = blockIdx.z;
    int i = (blockIdx.y << 4) + (threadIdx.x >> 4);
    int j = (blockIdx.x << 4) + (threadIdx.x & 15);
    const float4* Ai4 = (const float4*)(A + (size_t)(n * SP + i) * H1);
    const float4* Aj4 = (const float4*)(A + (size_t)(n * SP + j) * H1);

    // ---- layer 2: a2 = relu(Ai+Aj) @ W1 + b1 ----
    // NOTE: a2 must ONLY be indexed with compile-time constants (rule #20) —
    // in R1 a partially-unrolled a2[k] read forced the array to scratch
    // (VGPR=44, 252 MB scratch writes).
    float a2[H2];
#pragma unroll
    for (int o = 0; o < H2; ++o) a2[o] = b1[o];          // uniform -> s_load
#pragma unroll 2
    for (int k4 = 0; k4 < H1 / 4; ++k4) {
        float4 ai = Ai4[k4], aj = Aj4[k4];               // global_load_dwordx4
        float x1[4] = { fmaxf(ai.x + aj.x, 0.0f), fmaxf(ai.y + aj.y, 0.0f),
                        fmaxf(ai.z + aj.z, 0.0f), fmaxf(ai.w + aj.w, 0.0f) };
#pragma unroll
        for (int u = 0; u < 4; ++u) {
            const float* w = W1 + (k4 * 4 + u) * H2;     // wave-uniform -> s_load
#pragma unroll
            for (int o = 0; o < H2; ++o)
                a2[o] = fmaf(x1[u], w[o], a2[o]);
        }
    }

    // ---- layer 3: a3 = relu(a2) @ W2 + b2 ----
    // FULL unroll so a2[k] stays a compile-time index.
    float a3[H3];
#pragma unroll
    for (int o = 0; o < H3; ++o) a3[o] = b2[o];
#pragma unroll
    for (int k = 0; k < H2; ++k) {
        float x2 = fmaxf(a2[k], 0.0f);
#pragma unroll
        for (int o = 0; o < H3; ++o)
            a3[o] = fmaf(x2, W2[k * H3 + o], a3[o]);
    }

    // ---- layer 4: z = relu(a3) @ W3 + b3 ----
    float zp0 = 0.f, zp1 = 0.f, zp2 = 0.f, zp3 = 0.f;
#pragma unroll
    for (int k = 0; k < H3; k += 4) {
        zp0 = fmaf(fmaxf(a3[k + 0], 0.0f), W3[k + 0], zp0);
        zp1 = fmaf(fmaxf(a3[k + 1], 0.0f), W3[k + 1], zp1);
        zp2 = fmaf(fmaxf(a3[k + 2], 0.0f), W3[k + 2], zp2);
        zp3 = fmaf(fmaxf(a3[k + 3], 0.0f), W3[k + 3], zp3);
    }
    float z = b3[0] + ((zp0 + zp1) + (zp2 + zp3));

    size_t idx = ((size_t)n * SP + i) * SP + j;
    pred[idx] = z;

    // stable BCE-with-logits * mask * positiveMask
    float tg = heat[idx], mk = mask[idx], pm = pos[idx];
    float l = fmaxf(z, 0.0f) - z * tg + log1pf(expf(-fabsf(z)));
    float num = l * mk * pm;
    float den = pm;

    // wave(64)-level reduce, then cross-wave via LDS, one atomic pair per block
#pragma unroll
    for (int off = 32; off > 0; off >>= 1) {
        num += __shfl_down(num, off, 64);
        den += __shfl_down(den, off, 64);
    }
    __shared__ float rb[8];
    int lane = threadIdx.x & 63, wid = threadIdx.x >> 6;
    if (lane == 0) { rb[wid] = num; rb[4 + wid] = den; }
    __syncthreads();
    if (threadIdx.x == 0) {
        atomicAdd(&accum[0], (rb[0] + rb[1]) + (rb[2] + rb[3]));
        atomicAdd(&accum[1], (rb[4] + rb[5]) + (rb[6] + rb[7]));
    }
}

__global__ void k_final(const float* __restrict__ accum, float* __restrict__ out)
{
    out[0] = accum[0] / accum[1];
}

extern "C" void kernel_launch(void* const* d_in, const int* in_sizes, int n_in,
                              void* d_out, int out_size, void* d_ws, size_t ws_size,
                              hipStream_t stream)
{
    const float* points = (const float*)d_in[0];
    const float* heat   = (const float*)d_in[1];
    const float* mask   = (const float*)d_in[2];
    const float* pos    = (const float*)d_in[3];
    const float* W0     = (const float*)d_in[4];
    const float* b0     = (const float*)d_in[5];
    const float* W1     = (const float*)d_in[6];
    const float* b1     = (const float*)d_in[7];
    const float* W2     = (const float*)d_in[8];
    const float* b2     = (const float*)d_in[9];
    const float* W3     = (const float*)d_in[10];
    const float* b3     = (const float*)d_in[11];

    float* pred  = (float*)d_out;                       // (2,512,512)
    float* loss  = pred + (size_t)N_ * SP * SP;         // scalar
    float* accum = (float*)d_ws;                        // [0]=num, [1]=den
    float* A     = (float*)((char*)d_ws + 256);         // 2*512*128 f32 = 512 KiB

    hipMemsetAsync(d_ws, 0, 256, stream);
    k_precompA<<<N_ * SP, H1, 0, stream>>>(points, W0, b0, A);
    k_main<<<dim3(SP / 16, SP / 16, N_), 256, 0, stream>>>(
        A, W1, b1, W2, b2, W3, b3, heat, mask, pos, pred, accum);
    k_final<<<1, 1, 0, stream>>>(accum, loss);
}